// Round 3
// baseline (41.315 us; speedup 1.0000x reference)
//
#include <hip/hip_runtime.h>

#define NGRAM 4
#define KDIM 121
#define GDIM 5
#define FEPS 1e-9f
#define NKDIM (NGRAM * KDIM)      // 484 floats per [4,121] block
#define GNKDIM (GDIM * NKDIM)     // 2420
#define NCOMBO 81                 // 3^4
#define NV4 121                   // float4s per 484-float block

__device__ __forceinline__ float pick3(int s, float x0, float x1, float x2) {
    return (s == 0) ? x0 : ((s == 1) ? x1 : x2);
}

// 2 waves (128 threads) per batch element; 2 elements per 256-thread block.
__global__ __launch_bounds__(256, 8) void bleu_kernel(
    const float* __restrict__ tc_res,   // [B,1,4,121]
    const float* __restrict__ tc_gts,   // [B,5,4,121]
    const float* __restrict__ l_res,    // [B,1]
    const float* __restrict__ l_gts,    // [B,5]
    float* __restrict__ o_score,        // [B]
    float* __restrict__ o_slist,        // [B,81]
    float* __restrict__ o_judge,        // [B,4,121]
    float* __restrict__ o_sdl,          // [B]
    int B)
{
    const int tid  = threadIdx.x;
    const int half = tid >> 7;          // which element within the block
    const int t2   = tid & 127;         // index within the 128-thread group
    const int lane = tid & 63;
    const int wv   = (tid >> 6) & 1;    // which wave within the group
    const int b    = blockIdx.x * 2 + half;
    const bool valid = (b < B);

    float a0 = 0.0f, a1 = 0.0f, a2 = 0.0f, a3 = 0.0f;

    if (valid && t2 < NV4) {
        const float4* __restrict__ res4 = (const float4*)(tc_res + (size_t)b * NKDIM);
        const float4* __restrict__ gts4 = (const float4*)(tc_gts + (size_t)b * GNKDIM);
        const int vi = t2;

        const float4 g  = res4[vi];
        const float4 m0 = gts4[0 * NV4 + vi];
        const float4 m1 = gts4[1 * NV4 + vi];
        const float4 m2 = gts4[2 * NV4 + vi];
        const float4 m3 = gts4[3 * NV4 + vi];
        const float4 m4 = gts4[4 * NV4 + vi];

        const float mx = fmaxf(fmaxf(fmaxf(m0.x, m1.x), fmaxf(m2.x, m3.x)), m4.x) + FEPS;
        const float my = fmaxf(fmaxf(fmaxf(m0.y, m1.y), fmaxf(m2.y, m3.y)), m4.y) + FEPS;
        const float mz = fmaxf(fmaxf(fmaxf(m0.z, m1.z), fmaxf(m2.z, m3.z)), m4.z) + FEPS;
        const float mw = fmaxf(fmaxf(fmaxf(m0.w, m1.w), fmaxf(m2.w, m3.w)), m4.w) + FEPS;

        float4 j;
        j.x = (g.x <= mx) ? 1.0f : 0.0f;
        j.y = (g.y <= my) ? 1.0f : 0.0f;
        j.z = (g.z <= mz) ? 1.0f : 0.0f;
        j.w = (g.w <= mw) ? 1.0f : 0.0f;
        ((float4*)(o_judge + (size_t)b * NKDIM))[vi] = j;

        const float cx = fminf(g.x, mx);
        const float cy = fminf(g.y, my);
        const float cz = fminf(g.z, mz);
        const float cw = fminf(g.w, mw);

        const int idx = vi * 4;
        const int n0 = (idx >= KDIM) + (idx >= 2 * KDIM) + (idx >= 3 * KDIM);
        const int n3 = (idx + 3 >= KDIM) + (idx + 3 >= 2 * KDIM) + (idx + 3 >= 3 * KDIM);
        if (n0 == n3) {
            const float s = (cx + cy) + (cz + cw);
            a0 += (n0 == 0) ? s : 0.0f;
            a1 += (n0 == 1) ? s : 0.0f;
            a2 += (n0 == 2) ? s : 0.0f;
            a3 += (n0 == 3) ? s : 0.0f;
        } else {
            const float ce[4] = { cx, cy, cz, cw };
            #pragma unroll
            for (int e = 0; e < 4; ++e) {
                const int ie = idx + e;
                const int ne = (ie >= KDIM) + (ie >= 2 * KDIM) + (ie >= 3 * KDIM);
                const float v = ce[e];
                a0 += (ne == 0) ? v : 0.0f;
                a1 += (ne == 1) ? v : 0.0f;
                a2 += (ne == 2) ? v : 0.0f;
                a3 += (ne == 3) ? v : 0.0f;
            }
        }
    }

    // intra-wave reduction
    #pragma unroll
    for (int s = 1; s < 64; s <<= 1) {
        a0 += __shfl_xor(a0, s, 64);
        a1 += __shfl_xor(a1, s, 64);
        a2 += __shfl_xor(a2, s, 64);
        a3 += __shfl_xor(a3, s, 64);
    }

    // cross-wave combine (2 waves per element) via LDS
    __shared__ float4 red[2][2];
    if (lane == 0) red[half][wv] = make_float4(a0, a1, a2, a3);
    __syncthreads();
    const float4 r0 = red[half][0];
    const float4 r1 = red[half][1];
    const float s0 = r0.x + r1.x;
    const float s1 = r0.y + r1.y;
    const float s2 = r0.z + r1.z;
    const float s3 = r0.w + r1.w;

    if (!valid) return;

    // ---- scalar epilogue (redundant across the 128-thread group) ----
    const float l_i = l_res[b];
    float best_d = 1e30f;
    float l_r = 0.0f;
    #pragma unroll
    for (int g = 0; g < GDIM; ++g) {
        float lg = l_gts[(size_t)b * GDIM + g];
        lg = (lg == 0.0f) ? 200.0f : lg;      // LEN_MAX*10
        const float d = fabsf(l_i - lg);
        if (d < best_d) { best_d = d; l_r = lg; }   // strict < -> first argmin
    }

    const float li_e = l_i + FEPS;
    const float und = 1.0f / li_e;
    const float r = (l_r + FEPS) / li_e;
    // In f32, 1.0+1e-9 == 1.0f (matches JAX f32 arithmetic)
    const float lf = expf(1.0f - fmaxf(1.0f, r));

    const float gf0 = s0 * und;
    const float gf1 = s1 * und;
    const float gf2 = s2 * und;
    const float gf3 = s3 * und;

    // channels: 0 = gf, 1 = gf + und, 2 = relu(gf - und)
    const float c00 = gf0, c01 = gf1, c02 = gf2, c03 = gf3;
    const float c10 = gf0 + und, c11 = gf1 + und, c12 = gf2 + und, c13 = gf3 + und;
    const float c20 = fmaxf(gf0 - und, 0.0f);
    const float c21 = fmaxf(gf1 - und, 0.0f);
    const float c22 = fmaxf(gf2 - und, 0.0f);
    const float c23 = fmaxf(gf3 - und, 0.0f);

    const float p_last = c20 * c21 * c22 * c23;
    const float cf_last = lf * sqrtf(sqrtf(p_last));

    if (t2 < NCOMBO) {
        const int c = t2;
        const int i = c / 27;
        const int j = (c / 9) % 3;
        const int kk = (c / 3) % 3;
        const int l = c % 3;
        const float p = pick3(i, c00, c10, c20) *
                        pick3(j, c01, c11, c21) *
                        pick3(kk, c02, c12, c22) *
                        pick3(l, c03, c13, c23);
        const float cf = lf * sqrtf(sqrtf(p));
        o_slist[(size_t)b * NCOMBO + c] = cf - cf_last;
        if (c == 0) {
            o_score[b] = cf;   // combo 0 is all-channel-0 = the score
            const float base = gf0 * gf1 * gf2 * gf3;
            // JAX max-tie gradient: w = 1 if r>1, 0.5 if r==1, 0 if r<1
            const float w = (r > 1.0f) ? 1.0f : ((r == 1.0f) ? 0.5f : 0.0f);
            o_sdl[b] = sqrtf(sqrtf(base)) * lf * w * (l_r + FEPS) / (li_e * li_e);
        }
    }
}

extern "C" void kernel_launch(void* const* d_in, const int* in_sizes, int n_in,
                              void* d_out, int out_size, void* d_ws, size_t ws_size,
                              hipStream_t stream) {
    const float* tc_res = (const float*)d_in[0];
    const float* tc_gts = (const float*)d_in[1];
    const float* l_res  = (const float*)d_in[2];
    const float* l_gts  = (const float*)d_in[3];
    const int B = in_sizes[2];   // l_res has B elements

    float* out = (float*)d_out;
    float* o_score = out;
    float* o_slist = o_score + B;
    float* o_judge = o_slist + (size_t)B * NCOMBO;
    float* o_sdl   = o_judge + (size_t)B * NKDIM;

    const int blocks = (B + 1) / 2;            // 2 elements per 256-thread block
    bleu_kernel<<<blocks, 256, 0, stream>>>(tc_res, tc_gts, l_res, l_gts,
                                            o_score, o_slist, o_judge, o_sdl, B);
}